// Round 6
// baseline (1048.456 us; speedup 1.0000x reference)
//
#include <hip/hip_runtime.h>
#include <cstdint>
#include <cstddef>

// dims
#define G_    16
#define A_    64
#define P_    32
#define DIN_  768
#define DEMB_ 384
#define HP_   256
#define HA_   128
#define GA_   1024
#define N1_   1024
#define N2_   512
#define TCH   16          // timesteps per chunk

typedef float    f32x4   __attribute__((ext_vector_type(4)));
typedef _Float16 half8_t __attribute__((ext_vector_type(8)));
typedef _Float16 half4_t __attribute__((ext_vector_type(4)));

__device__ __forceinline__ float sigmoidf_(float x) { return 1.0f / (1.0f + __expf(-x)); }
__device__ __forceinline__ float tanhf_(float x) { return 2.0f / (1.0f + __expf(-2.0f * x)) - 1.0f; }
__device__ __forceinline__ _Float16 us2h(unsigned short u) { _Float16 h; __builtin_memcpy(&h, &u, 2); return h; }
__device__ __forceinline__ unsigned short h2us(_Float16 h) { unsigned short u; __builtin_memcpy(&u, &h, 2); return u; }

// ---------------- prep kernels ----------------

// Bmat[k][n] = sum_d w_embed[k][d] * k_post[d][n]   (f32, 768x1024)
__global__ __launch_bounds__(256) void k_wk(const float* __restrict__ w_embed,
                                            const float* __restrict__ k_post,
                                            float* __restrict__ Bmat) {
    int j  = blockIdx.x * 256 + threadIdx.x;
    int k0 = blockIdx.y * 4;
    float acc0 = 0.f, acc1 = 0.f, acc2 = 0.f, acc3 = 0.f;
    for (int d = 0; d < DEMB_; ++d) {
        float kp = k_post[(size_t)d * N1_ + j];
        acc0 += w_embed[(size_t)(k0 + 0) * DEMB_ + d] * kp;
        acc1 += w_embed[(size_t)(k0 + 1) * DEMB_ + d] * kp;
        acc2 += w_embed[(size_t)(k0 + 2) * DEMB_ + d] * kp;
        acc3 += w_embed[(size_t)(k0 + 3) * DEMB_ + d] * kp;
    }
    Bmat[(size_t)(k0 + 0) * N1_ + j] = acc0;
    Bmat[(size_t)(k0 + 1) * N1_ + j] = acc1;
    Bmat[(size_t)(k0 + 2) * N1_ + j] = acc2;
    Bmat[(size_t)(k0 + 3) * N1_ + j] = acc3;
}

// permuted bias: n = (p>>6)*16 + (p&15) + 256*((p>>4)&3)
__global__ __launch_bounds__(256) void k_bias_p(const float* __restrict__ b_embed,
                                                const float* __restrict__ k_post,
                                                const float* __restrict__ b_post,
                                                float* __restrict__ biasZp) {
    int p = blockIdx.x * 256 + threadIdx.x;
    int n = (p >> 6) * 16 + (p & 15) + 256 * ((p >> 4) & 3);
    float acc = b_post[n];
    for (int d = 0; d < DEMB_; ++d)
        acc += b_embed[d] * k_post[(size_t)d * N1_ + n];
    biasZp[p] = acc;
}

// transpose + permute Bmat[k][n] f32 -> Bt16[p][k] fp16 (k<768 only)
__global__ __launch_bounds__(256) void k_t16(const float* __restrict__ Bmat,
                                             _Float16* __restrict__ Bt16) {
    __shared__ float tile[64][65];
    const int tid = threadIdx.x;
    const int p0 = blockIdx.x * 64;
    const int k0 = blockIdx.y * 64;
    const int jgrp = p0 >> 6;
#pragma unroll
    for (int i = 0; i < 16; ++i) {
        int idx = i * 256 + tid;
        int pp = idx & 63, kk = idx >> 6;
        int n = jgrp * 16 + (pp & 15) + 256 * ((pp >> 4) & 3);
        tile[pp][kk] = Bmat[(size_t)(k0 + kk) * N1_ + n];
    }
    __syncthreads();
    const int pp = tid >> 2;
    const int kq = (tid & 3) * 16;
    _Float16 buf[16];
#pragma unroll
    for (int i = 0; i < 16; ++i) buf[i] = (_Float16)tile[pp][kq + i];
    _Float16* dst = &Bt16[(size_t)(p0 + pp) * DIN_ + k0 + kq];
    *(half8_t*)dst       = *(half8_t*)&buf[0];
    *(half8_t*)(dst + 8) = *(half8_t*)&buf[8];
}

// r_post -> fragment-major fp16: Bfrag[((fn*8+kt)*64+l)*8+s]
__global__ __launch_bounds__(256) void k_bfrag(const float* __restrict__ r_post,
                                               _Float16* __restrict__ Bfrag) {
    int idx = blockIdx.x * 256 + threadIdx.x;   // 0..32767
    int pt = idx >> 9;
    int kt = (idx >> 6) & 7;
    int l  = idx & 63;
    int p = pt * 16 + (l & 15);
    int n = (p >> 6) * 16 + (p & 15) + 256 * ((p >> 4) & 3);
    int kb = kt * 32 + (l >> 4) * 8;
    _Float16 buf[8];
#pragma unroll
    for (int s = 0; s < 8; ++s) buf[s] = (_Float16)r_post[(size_t)(kb + s) * N1_ + n];
    *(half8_t*)&Bfrag[(size_t)idx * 8] = *(half8_t*)buf;
}

// ---------------- Z GEMM: Z = x @ WK + bias, fp16 2-pass, quadruple-permuted fp16 out ----------------
#define ZBM 128
#define ZBN 256
#define ZBK 32
#define ZPAD 40

__global__ __launch_bounds__(512, 2) void k_zgemm(const float* __restrict__ x,
                                                  const _Float16* __restrict__ Bt16,
                                                  const float* __restrict__ biasZp,
                                                  _Float16* __restrict__ Zq, int tbase) {
    __shared__ union {
        struct { _Float16 AsH[ZBM][ZPAD], AsL[ZBM][ZPAD], Bs[ZBN][ZPAD]; } S;
        _Float16 Hs[64][264];
    } u;

    const int bid = blockIdx.x;                   // 0..511
    const int wg  = (bid & 7) * 64 + (bid >> 3);  // XCD swizzle
    const int bm  = (wg & 127) * ZBM;
    const int bn  = (wg >> 7) * ZBN;
    const int tid = threadIdx.x;

    const int arow = tid >> 2, akq = (tid & 3) * 8;
    const int brow = tid >> 1, bkq = (tid & 1) * 16;
    const int lane = tid & 63, w = tid >> 6;
    const int wm = (w >> 2) * 64, wn = (w & 3) * 64;
    const int frc = lane & 15, frk = (lane >> 4) * 8;

    const int crow = bm + arow;
    const size_t xrow = (size_t)(crow >> 4) * P_ + tbase + (crow & 15);
    const float*    aptr = &x[xrow * DIN_ + akq];
    const _Float16* bptr = &Bt16[(size_t)(bn + brow) * DIN_ + bkq];

    f32x4 acc[4][4];
#pragma unroll
    for (int i = 0; i < 4; ++i)
#pragma unroll
        for (int j = 0; j < 4; ++j) acc[i][j] = (f32x4)0.0f;

    float4 a0 = *(const float4*)aptr;
    float4 a1 = *(const float4*)(aptr + 4);
    uint4  b0 = *(const uint4*)bptr;
    uint4  b1 = *(const uint4*)(bptr + 8);

    const int NK = DIN_ / ZBK;   // 24
    for (int kt = 0; kt < NK; ++kt) {
        const int kn = (kt + 1 < NK) ? (kt + 1) * ZBK : kt * ZBK;
        float4 na0 = *(const float4*)(aptr + kn);
        float4 na1 = *(const float4*)(aptr + kn + 4);
        uint4  nb0 = *(const uint4*)(bptr + kn);
        uint4  nb1 = *(const uint4*)(bptr + kn + 8);

        half8_t ahv, alv;
        {
            float av[8] = {a0.x,a0.y,a0.z,a0.w,a1.x,a1.y,a1.z,a1.w};
#pragma unroll
            for (int i = 0; i < 8; ++i) {
                _Float16 hh = (_Float16)av[i];
                ahv[i] = hh;
                alv[i] = (_Float16)(av[i] - (float)hh);
            }
        }

        __syncthreads();
        *(half8_t*)&u.S.AsH[arow][akq] = ahv;
        *(half8_t*)&u.S.AsL[arow][akq] = alv;
        *(uint4*)&u.S.Bs[brow][bkq]     = b0;
        *(uint4*)&u.S.Bs[brow][bkq + 8] = b1;
        __syncthreads();

        half8_t bf[4];
#pragma unroll
        for (int fn = 0; fn < 4; ++fn)
            bf[fn] = *(const half8_t*)&u.S.Bs[wn + fn * 16 + frc][frk];
#pragma unroll
        for (int fm = 0; fm < 4; ++fm) {
            half8_t aH = *(const half8_t*)&u.S.AsH[wm + fm * 16 + frc][frk];
            half8_t aL = *(const half8_t*)&u.S.AsL[wm + fm * 16 + frc][frk];
#pragma unroll
            for (int fn = 0; fn < 4; ++fn)
                acc[fm][fn] = __builtin_amdgcn_mfma_f32_16x16x32_f16(aH, bf[fn], acc[fm][fn], 0, 0, 0);
#pragma unroll
            for (int fn = 0; fn < 4; ++fn)
                acc[fm][fn] = __builtin_amdgcn_mfma_f32_16x16x32_f16(aL, bf[fn], acc[fm][fn], 0, 0, 0);
        }
        a0 = na0; a1 = na1; b0 = nb0; b1 = nb1;
    }

    float bzv[4];
#pragma unroll
    for (int fn = 0; fn < 4; ++fn) bzv[fn] = biasZp[bn + wn + fn * 16 + frc];

#pragma unroll
    for (int half_ = 0; half_ < 2; ++half_) {
        __syncthreads();
        if ((w >> 2) == half_) {
#pragma unroll
            for (int fm = 0; fm < 4; ++fm)
#pragma unroll
                for (int fn = 0; fn < 4; ++fn)
#pragma unroll
                    for (int r = 0; r < 4; ++r) {
                        int rl = fm * 16 + (lane >> 4) * 4 + r;
                        int cl = wn + fn * 16 + frc;
                        int clp = ((cl >> 6) * 16 + (cl & 15)) * 4 + ((cl >> 4) & 3);
                        u.Hs[rl][clp] = (_Float16)(acc[fm][fn][r] + bzv[fn]);
                    }
        }
        __syncthreads();
#pragma unroll
        for (int i = 0; i < 4; ++i) {
            int id = i * 512 + tid;
            int r = id >> 5, cc = (id & 31) * 8;
            *(uint4*)&Zq[(size_t)(bm + half_ * 64 + r) * N1_ + bn + cc] = *(const uint4*)&u.Hs[r][cc];
        }
    }
}

// ---------------- recurrence: 128 blocks x 512 thr; weights fully on-chip; paired col-split ----------------
// Pair (b, b^8) shares rows rg*16..+15 (same XCD under %8 RR). Block computes 128 gate-hcols
// (half), exchanges its 8KB h-half with its sibling via L2 each step.
__global__ __launch_bounds__(512, 2) void k_rec(const _Float16* __restrict__ Zq,
                                                const _Float16* __restrict__ Bfrag,
                                                float* __restrict__ csave,
                                                unsigned int* __restrict__ hx,
                                                int* __restrict__ flags,
                                                float* __restrict__ hF32, int tbase) {
    __shared__ __align__(16) _Float16 hHs[4096];              // 8KB: h hi, A-frag layout
    __shared__ __align__(16) _Float16 hLs[4096];              // 8KB: h residual
    __shared__ __align__(16) _Float16 wlds[8 * 8 * 64 * 8];   // 64KB: q=3 weight frags [wv][kt][lane][8]

    const int tid = threadIdx.x, lane = tid & 63, wv = tid >> 6;  // wv 0..7
    const int hl = lane & 15, l4 = lane >> 4;
    const int b = blockIdx.x;
    const int rg   = ((b >> 4) << 3) | (b & 7);   // rowgroup 0..63
    const int half = (b >> 3) & 1;
    const int r0 = rg * 16;
    const int hcl = wv * 16 + hl;                 // local hcol 0..127
    const int hc  = half * 128 + hcl;             // global hcol 0..255
    const int fnb = half * 32 + wv * 4;           // global fn base of this wave

    // --- weights: 24 frags in VGPR (q=0..2), 8 frags in LDS (q=3); loaded once ---
    half8_t wreg[24];
#pragma unroll
    for (int q = 0; q < 3; ++q)
#pragma unroll
        for (int kt = 0; kt < 8; ++kt)
            wreg[q * 8 + kt] = *(const half8_t*)&Bfrag[(((size_t)(fnb + q) * 8 + kt) * 64 + lane) * 8];
#pragma unroll
    for (int kt = 0; kt < 8; ++kt) {
        half8_t w3 = *(const half8_t*)&Bfrag[(((size_t)(fnb + 3) * 8 + kt) * 64 + lane) * 8];
        *(half8_t*)&wlds[((wv * 8 + kt) * 64 + lane) * 8] = w3;
    }

    // --- state init ---
    float cst[4];
    if (tbase == 0) {
#pragma unroll
        for (int i = 0; i < 4; ++i) cst[i] = 0.f;
    } else {
        f32x4 cv = *(const f32x4*)&csave[((size_t)b * 512 + tid) * 4];
#pragma unroll
        for (int i = 0; i < 4; ++i) cst[i] = cv[i];
        // restore full h from hx (both halves)
#pragma unroll
        for (int hf = 0; hf < 2; ++hf)
#pragma unroll
            for (int rr = 0; rr < 4; ++rr) {
                int row = l4 * 4 + rr;
                unsigned int v = hx[((size_t)(rg * 2 + hf) * 16 + row) * 128 + hcl];
                int hcg = hf * 128 + hcl;
                int lidx = (((hcg >> 5) * 64) + (((hcg & 31) >> 3) * 16 + row)) * 8 + (hcg & 7);
                hHs[lidx] = us2h((unsigned short)(v & 0xffffu));
                hLs[lidx] = us2h((unsigned short)(v >> 16));
            }
    }
    __syncthreads();

    for (int tt = 0; tt < TCH; ++tt) {
        const int t = tbase + tt;

        // Z gate-quads for this thread's hcol, rows l4*4+rr (issued early)
        half4_t zv[4];
#pragma unroll
        for (int rr = 0; rr < 4; ++rr)
            zv[rr] = *(const half4_t*)&Zq[((size_t)(r0 + l4 * 4 + rr) * TCH + tt) * N1_ + (size_t)hc * 4];

        f32x4 acc[4];
#pragma unroll
        for (int i = 0; i < 4; ++i) acc[i] = (f32x4)0.0f;

        if (t > 0) {
#pragma unroll
            for (int kt = 0; kt < 8; ++kt) {
                half8_t ah = *(const half8_t*)&hHs[(kt * 64 + lane) * 8];
                half8_t al = *(const half8_t*)&hLs[(kt * 64 + lane) * 8];
                half8_t b3 = *(const half8_t*)&wlds[((wv * 8 + kt) * 64 + lane) * 8];
#pragma unroll
                for (int q = 0; q < 3; ++q) {
                    acc[q] = __builtin_amdgcn_mfma_f32_16x16x32_f16(ah, wreg[q * 8 + kt], acc[q], 0, 0, 0);
                    acc[q] = __builtin_amdgcn_mfma_f32_16x16x32_f16(al, wreg[q * 8 + kt], acc[q], 0, 0, 0);
                }
                acc[3] = __builtin_amdgcn_mfma_f32_16x16x32_f16(ah, b3, acc[3], 0, 0, 0);
                acc[3] = __builtin_amdgcn_mfma_f32_16x16x32_f16(al, b3, acc[3], 0, 0, 0);
            }
        }
        __syncthreads();   // all h reads of this step complete

        // epilogue: 4 rows, gates thread-local via q
        unsigned int packed[4];
        const bool last = (t == P_ - 1);
#pragma unroll
        for (int rr = 0; rr < 4; ++rr) {
            float gi = acc[0][rr] + (float)zv[rr][0];
            float gf = acc[1][rr] + (float)zv[rr][1];
            float gg = acc[2][rr] + (float)zv[rr][2];
            float go = acc[3][rr] + (float)zv[rr][3];
            float cn = sigmoidf_(gf) * cst[rr] + sigmoidf_(gi) * tanhf_(gg);
            cst[rr] = cn;
            float hv = sigmoidf_(go) * tanhf_(cn);
            int row = l4 * 4 + rr;
            _Float16 hh = (_Float16)hv;
            _Float16 hlo = (_Float16)(hv - (float)hh);
            int lidx = (((hc >> 5) * 64) + (((hc & 31) >> 3) * 16 + row)) * 8 + (hc & 7);
            hHs[lidx] = hh;
            hLs[lidx] = hlo;
            packed[rr] = (unsigned int)h2us(hh) | ((unsigned int)h2us(hlo) << 16);
            if (last) hF32[(size_t)(r0 + row) * HP_ + hc] = hv;
        }

        if (tt == TCH - 1) {
            if (tbase == 0) {   // persist own h-half for chunk 2
#pragma unroll
                for (int rr = 0; rr < 4; ++rr)
                    hx[((size_t)(rg * 2 + half) * 16 + (l4 * 4 + rr)) * 128 + hcl] = packed[rr];
            }
        } else {
            // ---- pair exchange of h halves through L2 ----
#pragma unroll
            for (int rr = 0; rr < 4; ++rr)
                hx[((size_t)(rg * 2 + half) * 16 + (l4 * 4 + rr)) * 128 + hcl] = packed[rr];
            __threadfence();
            __syncthreads();
            if (tid == 0) {
                __hip_atomic_store(&flags[rg * 64 + half * 32 + t], 1,
                                   __ATOMIC_RELEASE, __HIP_MEMORY_SCOPE_AGENT);
                while (__hip_atomic_load(&flags[rg * 64 + (half ^ 1) * 32 + t],
                                         __ATOMIC_ACQUIRE, __HIP_MEMORY_SCOPE_AGENT) == 0)
                    __builtin_amdgcn_s_sleep(1);
            }
            __syncthreads();
#pragma unroll
            for (int rr = 0; rr < 4; ++rr) {
                int row = l4 * 4 + rr;
                unsigned int v = hx[((size_t)(rg * 2 + (half ^ 1)) * 16 + row) * 128 + hcl];
                int hcp = (half ^ 1) * 128 + hcl;
                int lidx = (((hcp >> 5) * 64) + (((hcp & 31) >> 3) * 16 + row)) * 8 + (hcp & 7);
                hHs[lidx] = us2h((unsigned short)(v & 0xffffu));
                hLs[lidx] = us2h((unsigned short)(v >> 16));
            }
            __syncthreads();
        }
    }

    if (tbase == 0) {   // persist c for chunk 2
        f32x4 cv;
#pragma unroll
        for (int i = 0; i < 4; ++i) cv[i] = cst[i];
        *(f32x4*)&csave[((size_t)b * 512 + tid) * 4] = cv;
    }
}

// ---------------- author stage ----------------
__global__ __launch_bounds__(256) void k_zauth(const float* __restrict__ h,
                                               const float* __restrict__ k_auth,
                                               const float* __restrict__ b_auth,
                                               float* __restrict__ z_auth) {
    const int j = blockIdx.x * 256 + threadIdx.x;
    const int r0 = blockIdx.y * 4;
    float acc0 = b_auth[j], acc1 = acc0, acc2 = acc0, acc3 = acc0;
    for (int k = 0; k < HP_; ++k) {
        const float kp = k_auth[(size_t)k * N2_ + j];
        acc0 += h[(size_t)(r0 + 0) * HP_ + k] * kp;
        acc1 += h[(size_t)(r0 + 1) * HP_ + k] * kp;
        acc2 += h[(size_t)(r0 + 2) * HP_ + k] * kp;
        acc3 += h[(size_t)(r0 + 3) * HP_ + k] * kp;
    }
#pragma unroll
    for (int r = 0; r < 4; ++r) {
        const int b = r0 + r;
        const int g = b >> 6, a = b & 63;
        const float v = (r == 0) ? acc0 : (r == 1) ? acc1 : (r == 2) ? acc2 : acc3;
        z_auth[((size_t)a * G_ + g) * N2_ + j] = v;
    }
}

__global__ __launch_bounds__(1024) void k_author(const float* __restrict__ z_auth,
                                                 const float* __restrict__ r_auth,
                                                 float* __restrict__ out) {
    const int g = blockIdx.x;
    const int tid = threadIdx.x;
    const int j = tid >> 1;     // gate column 0..511
    const int kh = tid & 1;     // k half

    __shared__ float hs[HA_];
    __shared__ float gs[N2_];

    float rc[64];
#pragma unroll
    for (int kk = 0; kk < 64; ++kk)
        rc[kk] = r_auth[(size_t)(kh * 64 + kk) * N2_ + j];

    float cj = 0.f;
    if (tid < HA_) hs[tid] = 0.f;
    __syncthreads();

    for (int a = 0; a < A_; ++a) {
        float acc = kh ? 0.f : z_auth[((size_t)a * G_ + g) * N2_ + j];
#pragma unroll
        for (int kk = 0; kk < 64; ++kk)
            acc += hs[kh * 64 + kk] * rc[kk];
        acc += __shfl_xor(acc, 1);
        if (!kh) gs[j] = acc;
        __syncthreads();
        if (tid < HA_) {
            const float i_ = sigmoidf_(gs[tid]);
            const float f_ = sigmoidf_(gs[tid + 128]);
            const float gg = gs[tid + 256];
            const float o_ = sigmoidf_(gs[tid + 384]);
            cj = f_ * cj + i_ * tanhf_(gg);
            hs[tid] = o_ * tanhf_(cj);
        }
        __syncthreads();
    }
    if (tid < HA_) out[(size_t)g * HA_ + tid] = hs[tid];
}

// ---------------- launch ----------------
extern "C" void kernel_launch(void* const* d_in, const int* in_sizes, int n_in,
                              void* d_out, int out_size, void* d_ws, size_t ws_size,
                              hipStream_t stream) {
    const float* x       = (const float*)d_in[0];
    const float* w_embed = (const float*)d_in[1];
    const float* b_embed = (const float*)d_in[2];
    const float* k_post  = (const float*)d_in[3];
    const float* r_post  = (const float*)d_in[4];
    const float* b_post  = (const float*)d_in[5];
    const float* k_auth  = (const float*)d_in[6];
    const float* r_auth  = (const float*)d_in[7];
    const float* b_auth  = (const float*)d_in[8];
    float* out = (float*)d_out;

    char* wsb = (char*)d_ws;
    _Float16*     Zq     = (_Float16*)(wsb);                        // 32 MB (one chunk)
    float*        Bmat   = (float*)(wsb + (32ull << 20));           // 3 MB
    _Float16*     Bt16   = (_Float16*)(wsb + (36ull << 20));        // 1.5 MB
    _Float16*     Bfrag  = (_Float16*)(wsb + (38ull << 20));        // 512 KB
    float*        biasZp = (float*)(wsb + (38ull << 20) + (512ull << 10));  // 4 KB
    float*        csave  = (float*)(wsb + (39ull << 20));           // 1 MB
    unsigned int* hx     = (unsigned int*)(wsb + (40ull << 20));    // 1 MB exchange
    float*        hF32   = (float*)(wsb + (41ull << 20));           // 1 MB
    float*        z_auth = (float*)(wsb + (42ull << 20));           // 2 MB
    int*          flags  = (int*)(wsb + (44ull << 20));             // 16 KB

    hipMemsetAsync(flags, 0, 64 * 64 * sizeof(int), stream);

    // prep
    k_wk    <<<dim3(N1_ / 256, DIN_ / 4), 256, 0, stream>>>(w_embed, k_post, Bmat);
    k_bias_p<<<dim3(N1_ / 256), 256, 0, stream>>>(b_embed, k_post, b_post, biasZp);
    k_t16   <<<dim3(16, 12), 256, 0, stream>>>(Bmat, Bt16);
    k_bfrag <<<dim3(128), 256, 0, stream>>>(r_post, Bfrag);

    // two chunks of 16 timesteps
    for (int ch = 0; ch < 2; ++ch) {
        k_zgemm<<<dim3(512), 512, 0, stream>>>(x, Bt16, biasZp, Zq, ch * TCH);
        k_rec  <<<dim3(128), 512, 0, stream>>>(Zq, Bfrag, csave, hx, flags, hF32, ch * TCH);
    }

    // author stage
    k_zauth <<<dim3(N2_ / 256, GA_ / 4), 256, 0, stream>>>(hF32, k_auth, b_auth, z_auth);
    k_author<<<dim3(G_), 1024, 0, stream>>>(z_auth, r_auth, out);
}

// Round 7
// 414.256 us; speedup vs baseline: 2.5309x; 2.5309x over previous
//
#include <hip/hip_runtime.h>
#include <cstdint>
#include <cstddef>

// dims
#define G_    16
#define A_    64
#define P_    32
#define DIN_  768
#define DEMB_ 384
#define HP_   256
#define HA_   128
#define GA_   1024
#define N1_   1024
#define N2_   512
#define TCH   16          // timesteps per chunk

typedef float    f32x4   __attribute__((ext_vector_type(4)));
typedef _Float16 half8_t __attribute__((ext_vector_type(8)));
typedef _Float16 half4_t __attribute__((ext_vector_type(4)));

__device__ __forceinline__ float sigmoidf_(float x) { return 1.0f / (1.0f + __expf(-x)); }
__device__ __forceinline__ float tanhf_(float x) { return 2.0f / (1.0f + __expf(-2.0f * x)) - 1.0f; }
__device__ __forceinline__ _Float16 us2h(unsigned short u) { _Float16 h; __builtin_memcpy(&h, &u, 2); return h; }
__device__ __forceinline__ unsigned short h2us(_Float16 h) { unsigned short u; __builtin_memcpy(&u, &h, 2); return u; }

// ---------------- prep kernels ----------------

// Bmat[k][n] = sum_d w_embed[k][d] * k_post[d][n]   (f32, 768x1024)
__global__ __launch_bounds__(256) void k_wk(const float* __restrict__ w_embed,
                                            const float* __restrict__ k_post,
                                            float* __restrict__ Bmat) {
    int j  = blockIdx.x * 256 + threadIdx.x;
    int k0 = blockIdx.y * 4;
    float acc0 = 0.f, acc1 = 0.f, acc2 = 0.f, acc3 = 0.f;
    for (int d = 0; d < DEMB_; ++d) {
        float kp = k_post[(size_t)d * N1_ + j];
        acc0 += w_embed[(size_t)(k0 + 0) * DEMB_ + d] * kp;
        acc1 += w_embed[(size_t)(k0 + 1) * DEMB_ + d] * kp;
        acc2 += w_embed[(size_t)(k0 + 2) * DEMB_ + d] * kp;
        acc3 += w_embed[(size_t)(k0 + 3) * DEMB_ + d] * kp;
    }
    Bmat[(size_t)(k0 + 0) * N1_ + j] = acc0;
    Bmat[(size_t)(k0 + 1) * N1_ + j] = acc1;
    Bmat[(size_t)(k0 + 2) * N1_ + j] = acc2;
    Bmat[(size_t)(k0 + 3) * N1_ + j] = acc3;
}

// permuted bias: n = (p>>6)*16 + (p&15) + 256*((p>>4)&3)
__global__ __launch_bounds__(256) void k_bias_p(const float* __restrict__ b_embed,
                                                const float* __restrict__ k_post,
                                                const float* __restrict__ b_post,
                                                float* __restrict__ biasZp) {
    int p = blockIdx.x * 256 + threadIdx.x;
    int n = (p >> 6) * 16 + (p & 15) + 256 * ((p >> 4) & 3);
    float acc = b_post[n];
    for (int d = 0; d < DEMB_; ++d)
        acc += b_embed[d] * k_post[(size_t)d * N1_ + n];
    biasZp[p] = acc;
}

// transpose + permute Bmat[k][n] f32 -> Bt16[p][k] fp16 (k<768 only)
__global__ __launch_bounds__(256) void k_t16(const float* __restrict__ Bmat,
                                             _Float16* __restrict__ Bt16) {
    __shared__ float tile[64][65];
    const int tid = threadIdx.x;
    const int p0 = blockIdx.x * 64;
    const int k0 = blockIdx.y * 64;
    const int jgrp = p0 >> 6;
#pragma unroll
    for (int i = 0; i < 16; ++i) {
        int idx = i * 256 + tid;
        int pp = idx & 63, kk = idx >> 6;
        int n = jgrp * 16 + (pp & 15) + 256 * ((pp >> 4) & 3);
        tile[pp][kk] = Bmat[(size_t)(k0 + kk) * N1_ + n];
    }
    __syncthreads();
    const int pp = tid >> 2;
    const int kq = (tid & 3) * 16;
    _Float16 buf[16];
#pragma unroll
    for (int i = 0; i < 16; ++i) buf[i] = (_Float16)tile[pp][kq + i];
    _Float16* dst = &Bt16[(size_t)(p0 + pp) * DIN_ + k0 + kq];
    *(half8_t*)dst       = *(half8_t*)&buf[0];
    *(half8_t*)(dst + 8) = *(half8_t*)&buf[8];
}

// r_post -> fragment-major fp16: Bfrag[((fn*8+kt)*64+l)*8+s]
__global__ __launch_bounds__(256) void k_bfrag(const float* __restrict__ r_post,
                                               _Float16* __restrict__ Bfrag) {
    int idx = blockIdx.x * 256 + threadIdx.x;   // 0..32767
    int pt = idx >> 9;
    int kt = (idx >> 6) & 7;
    int l  = idx & 63;
    int p = pt * 16 + (l & 15);
    int n = (p >> 6) * 16 + (p & 15) + 256 * ((p >> 4) & 3);
    int kb = kt * 32 + (l >> 4) * 8;
    _Float16 buf[8];
#pragma unroll
    for (int s = 0; s < 8; ++s) buf[s] = (_Float16)r_post[(size_t)(kb + s) * N1_ + n];
    *(half8_t*)&Bfrag[(size_t)idx * 8] = *(half8_t*)buf;
}

// ---------------- Z GEMM: Z = x @ WK + bias, fp16 single-pass, quadruple-permuted fp16 out ----------------
#define ZBM 128
#define ZBN 256
#define ZBK 32
#define ZPAD 40

__global__ __launch_bounds__(512, 2) void k_zgemm(const float* __restrict__ x,
                                                  const _Float16* __restrict__ Bt16,
                                                  const float* __restrict__ biasZp,
                                                  _Float16* __restrict__ Zq, int tbase) {
    __shared__ union {
        struct { _Float16 As[ZBM][ZPAD], Bs[ZBN][ZPAD]; } S;
        _Float16 Hs[64][264];
    } u;

    const int bid = blockIdx.x;                   // 0..511
    const int wg  = (bid & 7) * 64 + (bid >> 3);  // XCD swizzle
    const int bm  = (wg & 127) * ZBM;
    const int bn  = (wg >> 7) * ZBN;
    const int tid = threadIdx.x;

    const int arow = tid >> 2, akq = (tid & 3) * 8;
    const int brow = tid >> 1, bkq = (tid & 1) * 16;
    const int lane = tid & 63, w = tid >> 6;
    const int wm = (w >> 2) * 64, wn = (w & 3) * 64;
    const int frc = lane & 15, frk = (lane >> 4) * 8;

    const int crow = bm + arow;
    const size_t xrow = (size_t)(crow >> 4) * P_ + tbase + (crow & 15);
    const float*    aptr = &x[xrow * DIN_ + akq];
    const _Float16* bptr = &Bt16[(size_t)(bn + brow) * DIN_ + bkq];

    f32x4 acc[4][4];
#pragma unroll
    for (int i = 0; i < 4; ++i)
#pragma unroll
        for (int j = 0; j < 4; ++j) acc[i][j] = (f32x4)0.0f;

    float4 a0 = *(const float4*)aptr;
    float4 a1 = *(const float4*)(aptr + 4);
    uint4  b0 = *(const uint4*)bptr;
    uint4  b1 = *(const uint4*)(bptr + 8);

    const int NK = DIN_ / ZBK;   // 24
    for (int kt = 0; kt < NK; ++kt) {
        const int kn = (kt + 1 < NK) ? (kt + 1) * ZBK : kt * ZBK;
        float4 na0 = *(const float4*)(aptr + kn);
        float4 na1 = *(const float4*)(aptr + kn + 4);
        uint4  nb0 = *(const uint4*)(bptr + kn);
        uint4  nb1 = *(const uint4*)(bptr + kn + 8);

        half8_t ahv;
        {
            float av[8] = {a0.x,a0.y,a0.z,a0.w,a1.x,a1.y,a1.z,a1.w};
#pragma unroll
            for (int i = 0; i < 8; ++i) ahv[i] = (_Float16)av[i];
        }

        __syncthreads();
        *(half8_t*)&u.S.As[arow][akq]  = ahv;
        *(uint4*)&u.S.Bs[brow][bkq]     = b0;
        *(uint4*)&u.S.Bs[brow][bkq + 8] = b1;
        __syncthreads();

        half8_t bf[4];
#pragma unroll
        for (int fn = 0; fn < 4; ++fn)
            bf[fn] = *(const half8_t*)&u.S.Bs[wn + fn * 16 + frc][frk];
#pragma unroll
        for (int fm = 0; fm < 4; ++fm) {
            half8_t aH = *(const half8_t*)&u.S.As[wm + fm * 16 + frc][frk];
#pragma unroll
            for (int fn = 0; fn < 4; ++fn)
                acc[fm][fn] = __builtin_amdgcn_mfma_f32_16x16x32_f16(aH, bf[fn], acc[fm][fn], 0, 0, 0);
        }
        a0 = na0; a1 = na1; b0 = nb0; b1 = nb1;
    }

    float bzv[4];
#pragma unroll
    for (int fn = 0; fn < 4; ++fn) bzv[fn] = biasZp[bn + wn + fn * 16 + frc];

#pragma unroll
    for (int half_ = 0; half_ < 2; ++half_) {
        __syncthreads();
        if ((w >> 2) == half_) {
#pragma unroll
            for (int fm = 0; fm < 4; ++fm)
#pragma unroll
                for (int fn = 0; fn < 4; ++fn)
#pragma unroll
                    for (int r = 0; r < 4; ++r) {
                        int rl = fm * 16 + (lane >> 4) * 4 + r;
                        int cl = wn + fn * 16 + frc;
                        int clp = ((cl >> 6) * 16 + (cl & 15)) * 4 + ((cl >> 4) & 3);
                        u.Hs[rl][clp] = (_Float16)(acc[fm][fn][r] + bzv[fn]);
                    }
        }
        __syncthreads();
#pragma unroll
        for (int i = 0; i < 4; ++i) {
            int id = i * 512 + tid;
            int r = id >> 5, cc = (id & 31) * 8;
            *(uint4*)&Zq[(size_t)(bm + half_ * 64 + r) * N1_ + bn + cc] = *(const uint4*)&u.Hs[r][cc];
        }
    }
}

// ---------------- recurrence: 64 blocks x 1024 thr, weights 3/4 resident, no cross-block sync ----------------
// Wave wv owns 16 hcols (hc=wv*16+hl) x 4 gates (fn=4wv+q). Weights:
// q=0,1 in VGPR (64 VGPR), q=2 in LDS (128KB), q=3 streamed from L2 (8KB/wave/step).
// h single-pass fp16, double-buffered in LDS; ONE barrier per step.
__global__ __launch_bounds__(1024, 4) void k_rec(const _Float16* __restrict__ Zq,
                                                 const _Float16* __restrict__ Bfrag,
                                                 float* __restrict__ csave,
                                                 unsigned short* __restrict__ hsave,
                                                 float* __restrict__ hF32, int tbase) {
    __shared__ __align__(16) _Float16 wlds[16 * 8 * 64 * 8];  // 128 KB: q=2 frags [wv][kt][lane][8]
    __shared__ __align__(16) _Float16 hbuf[2][4096];          // 16 KB: h double buffer, A-frag layout

    const int tid = threadIdx.x, lane = tid & 63, wv = tid >> 6;  // wv 0..15
    const int hl = lane & 15, l4 = lane >> 4;
    const int r0 = blockIdx.x * 16;
    const int hc = wv * 16 + hl;

    // --- resident weights ---
    half8_t wreg[16];
#pragma unroll
    for (int q = 0; q < 2; ++q)
#pragma unroll
        for (int kt = 0; kt < 8; ++kt)
            wreg[q * 8 + kt] = *(const half8_t*)&Bfrag[(((size_t)(4 * wv + q) * 8 + kt) * 64 + lane) * 8];
#pragma unroll
    for (int kt = 0; kt < 8; ++kt)
        *(half8_t*)&wlds[((wv * 8 + kt) * 64 + lane) * 8] =
            *(const half8_t*)&Bfrag[(((size_t)(4 * wv + 2) * 8 + kt) * 64 + lane) * 8];
    const _Float16* w3base = &Bfrag[((size_t)(4 * wv + 3) * 8 * 64 + lane) * 8];   // + kt*512

    // --- state init ---
    float cst[4];
    if (tbase == 0) {
#pragma unroll
        for (int i = 0; i < 4; ++i) cst[i] = 0.f;
    } else {
        f32x4 cv = *(const f32x4*)&csave[((size_t)blockIdx.x * 1024 + tid) * 4];
#pragma unroll
        for (int i = 0; i < 4; ++i) cst[i] = cv[i];
        // restore h into hbuf[0] (chunk2 starts at t=16, cur = 0)
#pragma unroll
        for (int rr = 0; rr < 4; ++rr) {
            int row = l4 * 4 + rr;
            int lidx = (((hc >> 5) * 64) + (((hc & 31) >> 3) * 16 + row)) * 8 + (hc & 7);
            hbuf[0][lidx] = us2h(hsave[((size_t)(r0 + row)) * HP_ + hc]);
        }
    }
    __syncthreads();

    for (int tt = 0; tt < TCH; ++tt) {
        const int t = tbase + tt;
        const int cur = t & 1, nxt = cur ^ 1;

        // Z gate-quads (issued early; L2/L3)
        half4_t zv[4];
#pragma unroll
        for (int rr = 0; rr < 4; ++rr)
            zv[rr] = *(const half4_t*)&Zq[((size_t)(r0 + l4 * 4 + rr) * TCH + tt) * N1_ + (size_t)hc * 4];

        f32x4 acc[4];
#pragma unroll
        for (int i = 0; i < 4; ++i) acc[i] = (f32x4)0.0f;

        if (t > 0) {
#pragma unroll
            for (int kt = 0; kt < 8; ++kt) {
                half8_t ah = *(const half8_t*)&hbuf[cur][(kt * 64 + lane) * 8];
                half8_t w3 = *(const half8_t*)&w3base[(size_t)kt * 512];
                half8_t b2 = *(const half8_t*)&wlds[((wv * 8 + kt) * 64 + lane) * 8];
                acc[0] = __builtin_amdgcn_mfma_f32_16x16x32_f16(ah, wreg[kt],     acc[0], 0, 0, 0);
                acc[1] = __builtin_amdgcn_mfma_f32_16x16x32_f16(ah, wreg[8 + kt], acc[1], 0, 0, 0);
                acc[2] = __builtin_amdgcn_mfma_f32_16x16x32_f16(ah, b2,           acc[2], 0, 0, 0);
                acc[3] = __builtin_amdgcn_mfma_f32_16x16x32_f16(ah, w3,           acc[3], 0, 0, 0);
            }
        }

        // epilogue: 4 rows, all 4 gates thread-local
        const bool last = (t == P_ - 1);
        const bool save = (tbase == 0) && (tt == TCH - 1);
#pragma unroll
        for (int rr = 0; rr < 4; ++rr) {
            float gi = acc[0][rr] + (float)zv[rr][0];
            float gf = acc[1][rr] + (float)zv[rr][1];
            float gg = acc[2][rr] + (float)zv[rr][2];
            float go = acc[3][rr] + (float)zv[rr][3];
            float cn = sigmoidf_(gf) * cst[rr] + sigmoidf_(gi) * tanhf_(gg);
            cst[rr] = cn;
            float hv = sigmoidf_(go) * tanhf_(cn);
            int row = l4 * 4 + rr;
            int lidx = (((hc >> 5) * 64) + (((hc & 31) >> 3) * 16 + row)) * 8 + (hc & 7);
            _Float16 hh = (_Float16)hv;
            hbuf[nxt][lidx] = hh;
            if (save) hsave[((size_t)(r0 + row)) * HP_ + hc] = h2us(hh);
            if (last) hF32[(size_t)(r0 + row) * HP_ + hc] = hv;
        }
        __syncthreads();   // writes to hbuf[nxt] visible; prior reads of hbuf[cur] done
    }

    if (tbase == 0) {
        f32x4 cv;
#pragma unroll
        for (int i = 0; i < 4; ++i) cv[i] = cst[i];
        *(f32x4*)&csave[((size_t)blockIdx.x * 1024 + tid) * 4] = cv;
    }
}

// ---------------- author stage ----------------
__global__ __launch_bounds__(256) void k_zauth(const float* __restrict__ h,
                                               const float* __restrict__ k_auth,
                                               const float* __restrict__ b_auth,
                                               float* __restrict__ z_auth) {
    const int j = blockIdx.x * 256 + threadIdx.x;
    const int r0 = blockIdx.y * 4;
    float acc0 = b_auth[j], acc1 = acc0, acc2 = acc0, acc3 = acc0;
    for (int k = 0; k < HP_; ++k) {
        const float kp = k_auth[(size_t)k * N2_ + j];
        acc0 += h[(size_t)(r0 + 0) * HP_ + k] * kp;
        acc1 += h[(size_t)(r0 + 1) * HP_ + k] * kp;
        acc2 += h[(size_t)(r0 + 2) * HP_ + k] * kp;
        acc3 += h[(size_t)(r0 + 3) * HP_ + k] * kp;
    }
#pragma unroll
    for (int r = 0; r < 4; ++r) {
        const int b = r0 + r;
        const int g = b >> 6, a = b & 63;
        const float v = (r == 0) ? acc0 : (r == 1) ? acc1 : (r == 2) ? acc2 : acc3;
        z_auth[((size_t)a * G_ + g) * N2_ + j] = v;
    }
}

__global__ __launch_bounds__(1024) void k_author(const float* __restrict__ z_auth,
                                                 const float* __restrict__ r_auth,
                                                 float* __restrict__ out) {
    const int g = blockIdx.x;
    const int tid = threadIdx.x;
    const int j = tid >> 1;     // gate column 0..511
    const int kh = tid & 1;     // k half

    __shared__ float hs[HA_];
    __shared__ float gs[N2_];

    float rc[64];
#pragma unroll
    for (int kk = 0; kk < 64; ++kk)
        rc[kk] = r_auth[(size_t)(kh * 64 + kk) * N2_ + j];

    float cj = 0.f;
    if (tid < HA_) hs[tid] = 0.f;
    __syncthreads();

    for (int a = 0; a < A_; ++a) {
        float acc = kh ? 0.f : z_auth[((size_t)a * G_ + g) * N2_ + j];
#pragma unroll
        for (int kk = 0; kk < 64; ++kk)
            acc += hs[kh * 64 + kk] * rc[kk];
        acc += __shfl_xor(acc, 1);
        if (!kh) gs[j] = acc;
        __syncthreads();
        if (tid < HA_) {
            const float i_ = sigmoidf_(gs[tid]);
            const float f_ = sigmoidf_(gs[tid + 128]);
            const float gg = gs[tid + 256];
            const float o_ = sigmoidf_(gs[tid + 384]);
            cj = f_ * cj + i_ * tanhf_(gg);
            hs[tid] = o_ * tanhf_(cj);
        }
        __syncthreads();
    }
    if (tid < HA_) out[(size_t)g * HA_ + tid] = hs[tid];
}

// ---------------- launch ----------------
extern "C" void kernel_launch(void* const* d_in, const int* in_sizes, int n_in,
                              void* d_out, int out_size, void* d_ws, size_t ws_size,
                              hipStream_t stream) {
    const float* x       = (const float*)d_in[0];
    const float* w_embed = (const float*)d_in[1];
    const float* b_embed = (const float*)d_in[2];
    const float* k_post  = (const float*)d_in[3];
    const float* r_post  = (const float*)d_in[4];
    const float* b_post  = (const float*)d_in[5];
    const float* k_auth  = (const float*)d_in[6];
    const float* r_auth  = (const float*)d_in[7];
    const float* b_auth  = (const float*)d_in[8];
    float* out = (float*)d_out;

    char* wsb = (char*)d_ws;
    _Float16*       Zq     = (_Float16*)(wsb);                        // 32 MB (one chunk)
    float*          Bmat   = (float*)(wsb + (32ull << 20));           // 3 MB
    _Float16*       Bt16   = (_Float16*)(wsb + (36ull << 20));        // 1.5 MB
    _Float16*       Bfrag  = (_Float16*)(wsb + (38ull << 20));        // 512 KB
    float*          biasZp = (float*)(wsb + (38ull << 20) + (512ull << 10));  // 4 KB
    float*          csave  = (float*)(wsb + (39ull << 20));           // 1 MB
    unsigned short* hsave  = (unsigned short*)(wsb + (40ull << 20));  // 512 KB
    float*          hF32   = (float*)(wsb + (41ull << 20));           // 1 MB
    float*          z_auth = (float*)(wsb + (42ull << 20));           // 2 MB

    // prep
    k_wk    <<<dim3(N1_ / 256, DIN_ / 4), 256, 0, stream>>>(w_embed, k_post, Bmat);
    k_bias_p<<<dim3(N1_ / 256), 256, 0, stream>>>(b_embed, k_post, b_post, biasZp);
    k_t16   <<<dim3(16, 12), 256, 0, stream>>>(Bmat, Bt16);
    k_bfrag <<<dim3(128), 256, 0, stream>>>(r_post, Bfrag);

    // two chunks of 16 timesteps
    for (int ch = 0; ch < 2; ++ch) {
        k_zgemm<<<dim3(512), 512, 0, stream>>>(x, Bt16, biasZp, Zq, ch * TCH);
        k_rec  <<<dim3(64), 1024, 0, stream>>>(Zq, Bfrag, csave, hsave, hF32, ch * TCH);
    }

    // author stage
    k_zauth <<<dim3(N2_ / 256, GA_ / 4), 256, 0, stream>>>(hF32, k_auth, b_auth, z_auth);
    k_author<<<dim3(G_), 1024, 0, stream>>>(z_auth, r_auth, out);
}

// Round 8
// 404.939 us; speedup vs baseline: 2.5892x; 1.0230x over previous
//
#include <hip/hip_runtime.h>
#include <cstdint>
#include <cstddef>

// dims
#define G_    16
#define A_    64
#define P_    32
#define DIN_  768
#define DEMB_ 384
#define HP_   256
#define HA_   128
#define GA_   1024
#define N1_   1024
#define N2_   512
#define TCH   16          // timesteps per chunk

typedef float    f32x4   __attribute__((ext_vector_type(4)));
typedef _Float16 half8_t __attribute__((ext_vector_type(8)));
typedef _Float16 half4_t __attribute__((ext_vector_type(4)));

__device__ __forceinline__ float sigmoidf_(float x) { return 1.0f / (1.0f + __expf(-x)); }
__device__ __forceinline__ float tanhf_(float x) { return 2.0f / (1.0f + __expf(-2.0f * x)) - 1.0f; }
__device__ __forceinline__ _Float16 us2h(unsigned short u) { _Float16 h; __builtin_memcpy(&h, &u, 2); return h; }
__device__ __forceinline__ unsigned short h2us(_Float16 h) { unsigned short u; __builtin_memcpy(&u, &h, 2); return u; }

// ---------------- prep kernels ----------------

// Bmat[k][n] = sum_d w_embed[k][d] * k_post[d][n]   (f32, 768x1024)
__global__ __launch_bounds__(256) void k_wk(const float* __restrict__ w_embed,
                                            const float* __restrict__ k_post,
                                            float* __restrict__ Bmat) {
    int j  = blockIdx.x * 256 + threadIdx.x;
    int k0 = blockIdx.y * 4;
    float acc0 = 0.f, acc1 = 0.f, acc2 = 0.f, acc3 = 0.f;
    for (int d = 0; d < DEMB_; ++d) {
        float kp = k_post[(size_t)d * N1_ + j];
        acc0 += w_embed[(size_t)(k0 + 0) * DEMB_ + d] * kp;
        acc1 += w_embed[(size_t)(k0 + 1) * DEMB_ + d] * kp;
        acc2 += w_embed[(size_t)(k0 + 2) * DEMB_ + d] * kp;
        acc3 += w_embed[(size_t)(k0 + 3) * DEMB_ + d] * kp;
    }
    Bmat[(size_t)(k0 + 0) * N1_ + j] = acc0;
    Bmat[(size_t)(k0 + 1) * N1_ + j] = acc1;
    Bmat[(size_t)(k0 + 2) * N1_ + j] = acc2;
    Bmat[(size_t)(k0 + 3) * N1_ + j] = acc3;
}

// permuted bias: n = (p>>6)*16 + (p&15) + 256*((p>>4)&3)
__global__ __launch_bounds__(256) void k_bias_p(const float* __restrict__ b_embed,
                                                const float* __restrict__ k_post,
                                                const float* __restrict__ b_post,
                                                float* __restrict__ biasZp) {
    int p = blockIdx.x * 256 + threadIdx.x;
    int n = (p >> 6) * 16 + (p & 15) + 256 * ((p >> 4) & 3);
    float acc = b_post[n];
    for (int d = 0; d < DEMB_; ++d)
        acc += b_embed[d] * k_post[(size_t)d * N1_ + n];
    biasZp[p] = acc;
}

// transpose + permute Bmat[k][n] f32 -> Bt16[p][k] fp16 (k<768 only)
__global__ __launch_bounds__(256) void k_t16(const float* __restrict__ Bmat,
                                             _Float16* __restrict__ Bt16) {
    __shared__ float tile[64][65];
    const int tid = threadIdx.x;
    const int p0 = blockIdx.x * 64;
    const int k0 = blockIdx.y * 64;
    const int jgrp = p0 >> 6;
#pragma unroll
    for (int i = 0; i < 16; ++i) {
        int idx = i * 256 + tid;
        int pp = idx & 63, kk = idx >> 6;
        int n = jgrp * 16 + (pp & 15) + 256 * ((pp >> 4) & 3);
        tile[pp][kk] = Bmat[(size_t)(k0 + kk) * N1_ + n];
    }
    __syncthreads();
    const int pp = tid >> 2;
    const int kq = (tid & 3) * 16;
    _Float16 buf[16];
#pragma unroll
    for (int i = 0; i < 16; ++i) buf[i] = (_Float16)tile[pp][kq + i];
    _Float16* dst = &Bt16[(size_t)(p0 + pp) * DIN_ + k0 + kq];
    *(half8_t*)dst       = *(half8_t*)&buf[0];
    *(half8_t*)(dst + 8) = *(half8_t*)&buf[8];
}

// r_post -> fragment-major fp16: Bfrag[((fn*8+kt)*64+l)*8+s]
__global__ __launch_bounds__(256) void k_bfrag(const float* __restrict__ r_post,
                                               _Float16* __restrict__ Bfrag) {
    int idx = blockIdx.x * 256 + threadIdx.x;   // 0..32767
    int pt = idx >> 9;
    int kt = (idx >> 6) & 7;
    int l  = idx & 63;
    int p = pt * 16 + (l & 15);
    int n = (p >> 6) * 16 + (p & 15) + 256 * ((p >> 4) & 3);
    int kb = kt * 32 + (l >> 4) * 8;
    _Float16 buf[8];
#pragma unroll
    for (int s = 0; s < 8; ++s) buf[s] = (_Float16)r_post[(size_t)(kb + s) * N1_ + n];
    *(half8_t*)&Bfrag[(size_t)idx * 8] = *(half8_t*)buf;
}

// ---------------- Z GEMM: Z = x @ WK + bias, fp16 single-pass ----------------
// Zq layout: [t_local][row][pcol]  (contiguous 2MB slab per timestep)
#define ZBM 128
#define ZBN 256
#define ZBK 32
#define ZPAD 40

__global__ __launch_bounds__(512, 2) void k_zgemm(const float* __restrict__ x,
                                                  const _Float16* __restrict__ Bt16,
                                                  const float* __restrict__ biasZp,
                                                  _Float16* __restrict__ Zq, int tbase) {
    __shared__ union {
        struct { _Float16 As[ZBM][ZPAD], Bs[ZBN][ZPAD]; } S;
        _Float16 Hs[64][264];
    } u;

    const int bid = blockIdx.x;                   // 0..511
    const int wg  = (bid & 7) * 64 + (bid >> 3);  // XCD swizzle
    const int bm  = (wg & 127) * ZBM;
    const int bn  = (wg >> 7) * ZBN;
    const int tid = threadIdx.x;

    const int arow = tid >> 2, akq = (tid & 3) * 8;
    const int brow = tid >> 1, bkq = (tid & 1) * 16;
    const int lane = tid & 63, w = tid >> 6;
    const int wm = (w >> 2) * 64, wn = (w & 3) * 64;
    const int frc = lane & 15, frk = (lane >> 4) * 8;

    const int crow = bm + arow;
    const size_t xrow = (size_t)(crow >> 4) * P_ + tbase + (crow & 15);
    const float*    aptr = &x[xrow * DIN_ + akq];
    const _Float16* bptr = &Bt16[(size_t)(bn + brow) * DIN_ + bkq];

    f32x4 acc[4][4];
#pragma unroll
    for (int i = 0; i < 4; ++i)
#pragma unroll
        for (int j = 0; j < 4; ++j) acc[i][j] = (f32x4)0.0f;

    float4 a0 = *(const float4*)aptr;
    float4 a1 = *(const float4*)(aptr + 4);
    uint4  b0 = *(const uint4*)bptr;
    uint4  b1 = *(const uint4*)(bptr + 8);

    const int NK = DIN_ / ZBK;   // 24
    for (int kt = 0; kt < NK; ++kt) {
        const int kn = (kt + 1 < NK) ? (kt + 1) * ZBK : kt * ZBK;
        float4 na0 = *(const float4*)(aptr + kn);
        float4 na1 = *(const float4*)(aptr + kn + 4);
        uint4  nb0 = *(const uint4*)(bptr + kn);
        uint4  nb1 = *(const uint4*)(bptr + kn + 8);

        half8_t ahv;
        {
            float av[8] = {a0.x,a0.y,a0.z,a0.w,a1.x,a1.y,a1.z,a1.w};
#pragma unroll
            for (int i = 0; i < 8; ++i) ahv[i] = (_Float16)av[i];
        }

        __syncthreads();
        *(half8_t*)&u.S.As[arow][akq]  = ahv;
        *(uint4*)&u.S.Bs[brow][bkq]     = b0;
        *(uint4*)&u.S.Bs[brow][bkq + 8] = b1;
        __syncthreads();

        half8_t bf[4];
#pragma unroll
        for (int fn = 0; fn < 4; ++fn)
            bf[fn] = *(const half8_t*)&u.S.Bs[wn + fn * 16 + frc][frk];
#pragma unroll
        for (int fm = 0; fm < 4; ++fm) {
            half8_t aH = *(const half8_t*)&u.S.As[wm + fm * 16 + frc][frk];
#pragma unroll
            for (int fn = 0; fn < 4; ++fn)
                acc[fm][fn] = __builtin_amdgcn_mfma_f32_16x16x32_f16(aH, bf[fn], acc[fm][fn], 0, 0, 0);
        }
        a0 = na0; a1 = na1; b0 = nb0; b1 = nb1;
    }

    float bzv[4];
#pragma unroll
    for (int fn = 0; fn < 4; ++fn) bzv[fn] = biasZp[bn + wn + fn * 16 + frc];

#pragma unroll
    for (int half_ = 0; half_ < 2; ++half_) {
        __syncthreads();
        if ((w >> 2) == half_) {
#pragma unroll
            for (int fm = 0; fm < 4; ++fm)
#pragma unroll
                for (int fn = 0; fn < 4; ++fn)
#pragma unroll
                    for (int r = 0; r < 4; ++r) {
                        int rl = fm * 16 + (lane >> 4) * 4 + r;
                        int cl = wn + fn * 16 + frc;
                        int clp = ((cl >> 6) * 16 + (cl & 15)) * 4 + ((cl >> 4) & 3);
                        u.Hs[rl][clp] = (_Float16)(acc[fm][fn][r] + bzv[fn]);
                    }
        }
        __syncthreads();
#pragma unroll
        for (int i = 0; i < 4; ++i) {
            int id = i * 512 + tid;
            int r = id >> 5, cc = (id & 31) * 8;
            int crow2 = bm + half_ * 64 + r;
            size_t zrow = (size_t)(crow2 & 15) * GA_ + (crow2 >> 4);   // [t][row]
            *(uint4*)&Zq[zrow * N1_ + bn + cc] = *(const uint4*)&u.Hs[r][cc];
        }
    }
}

// ---------------- recurrence: 64 blocks x 1024 thr; q0,q1 VGPR / q2 LDS / q3 L2-stream;
// Zq prefetched one full step ahead into registers ----------------
__global__ __launch_bounds__(1024, 4) void k_rec(const _Float16* __restrict__ Zq,
                                                 const _Float16* __restrict__ Bfrag,
                                                 float* __restrict__ csave,
                                                 unsigned short* __restrict__ hsave,
                                                 float* __restrict__ hF32, int tbase) {
    __shared__ __align__(16) _Float16 wlds[16 * 8 * 64 * 8];  // 128 KB: q=2 frags
    __shared__ __align__(16) _Float16 hbuf[2][4096];          // 16 KB: h double buffer

    const int tid = threadIdx.x, lane = tid & 63, wv = tid >> 6;  // wv 0..15
    const int hl = lane & 15, l4 = lane >> 4;
    const int r0 = blockIdx.x * 16;
    const int hc = wv * 16 + hl;

    // --- resident weights ---
    half8_t wreg[16];
#pragma unroll
    for (int q = 0; q < 2; ++q)
#pragma unroll
        for (int kt = 0; kt < 8; ++kt)
            wreg[q * 8 + kt] = *(const half8_t*)&Bfrag[(((size_t)(4 * wv + q) * 8 + kt) * 64 + lane) * 8];
#pragma unroll
    for (int kt = 0; kt < 8; ++kt)
        *(half8_t*)&wlds[((wv * 8 + kt) * 64 + lane) * 8] =
            *(const half8_t*)&Bfrag[(((size_t)(4 * wv + 2) * 8 + kt) * 64 + lane) * 8];
    const _Float16* w3base = &Bfrag[((size_t)(4 * wv + 3) * 8 * 64 + lane) * 8];   // + kt*512

    // --- state init ---
    float cst[4];
    if (tbase == 0) {
#pragma unroll
        for (int i = 0; i < 4; ++i) cst[i] = 0.f;
    } else {
        f32x4 cv = *(const f32x4*)&csave[((size_t)blockIdx.x * 1024 + tid) * 4];
#pragma unroll
        for (int i = 0; i < 4; ++i) cst[i] = cv[i];
#pragma unroll
        for (int rr = 0; rr < 4; ++rr) {
            int row = l4 * 4 + rr;
            int lidx = (((hc >> 5) * 64) + (((hc & 31) >> 3) * 16 + row)) * 8 + (hc & 7);
            hbuf[0][lidx] = us2h(hsave[((size_t)(r0 + row)) * HP_ + hc]);
        }
    }
    __syncthreads();

    // Zq per-thread base (layout [t][row][pcol]); prefetch tt=0
    const _Float16* zp = &Zq[((size_t)(r0 + l4 * 4)) * N1_ + (size_t)hc * 4];
    half4_t zvN[4];
#pragma unroll
    for (int rr = 0; rr < 4; ++rr)
        zvN[rr] = *(const half4_t*)&zp[(size_t)rr * N1_];

    for (int tt = 0; tt < TCH; ++tt) {
        const int t = tbase + tt;
        const int cur = t & 1, nxt = cur ^ 1;

        // consume-prev / issue-next Zq prefetch (one full step of latency cover)
        half4_t zv[4];
#pragma unroll
        for (int rr = 0; rr < 4; ++rr) zv[rr] = zvN[rr];
        zp += (size_t)GA_ * N1_;
        if (tt + 1 < TCH) {
#pragma unroll
            for (int rr = 0; rr < 4; ++rr)
                zvN[rr] = *(const half4_t*)&zp[(size_t)rr * N1_];
        }

        f32x4 acc[4];
#pragma unroll
        for (int i = 0; i < 4; ++i) acc[i] = (f32x4)0.0f;

        if (t > 0) {
#pragma unroll
            for (int kt = 0; kt < 8; ++kt) {
                half8_t ah = *(const half8_t*)&hbuf[cur][(kt * 64 + lane) * 8];
                half8_t b2 = *(const half8_t*)&wlds[((wv * 8 + kt) * 64 + lane) * 8];
                half8_t w3 = *(const half8_t*)&w3base[(size_t)kt * 512];
                acc[0] = __builtin_amdgcn_mfma_f32_16x16x32_f16(ah, wreg[kt],     acc[0], 0, 0, 0);
                acc[1] = __builtin_amdgcn_mfma_f32_16x16x32_f16(ah, wreg[8 + kt], acc[1], 0, 0, 0);
                acc[2] = __builtin_amdgcn_mfma_f32_16x16x32_f16(ah, b2,           acc[2], 0, 0, 0);
                acc[3] = __builtin_amdgcn_mfma_f32_16x16x32_f16(ah, w3,           acc[3], 0, 0, 0);
            }
        }

        // epilogue: 4 rows, all 4 gates thread-local
        const bool last = (t == P_ - 1);
        const bool save = (tbase == 0) && (tt == TCH - 1);
#pragma unroll
        for (int rr = 0; rr < 4; ++rr) {
            float gi = acc[0][rr] + (float)zv[rr][0];
            float gf = acc[1][rr] + (float)zv[rr][1];
            float gg = acc[2][rr] + (float)zv[rr][2];
            float go = acc[3][rr] + (float)zv[rr][3];
            float cn = sigmoidf_(gf) * cst[rr] + sigmoidf_(gi) * tanhf_(gg);
            cst[rr] = cn;
            float hv = sigmoidf_(go) * tanhf_(cn);
            int row = l4 * 4 + rr;
            int lidx = (((hc >> 5) * 64) + (((hc & 31) >> 3) * 16 + row)) * 8 + (hc & 7);
            _Float16 hh = (_Float16)hv;
            hbuf[nxt][lidx] = hh;
            if (save) hsave[((size_t)(r0 + row)) * HP_ + hc] = h2us(hh);
            if (last) hF32[(size_t)(r0 + row) * HP_ + hc] = hv;
        }
        __syncthreads();   // hbuf[nxt] visible; hbuf[cur] reads done
    }

    if (tbase == 0) {
        f32x4 cv;
#pragma unroll
        for (int i = 0; i < 4; ++i) cv[i] = cst[i];
        *(f32x4*)&csave[((size_t)blockIdx.x * 1024 + tid) * 4] = cv;
    }
}

// ---------------- author stage ----------------
__global__ __launch_bounds__(256) void k_zauth(const float* __restrict__ h,
                                               const float* __restrict__ k_auth,
                                               const float* __restrict__ b_auth,
                                               float* __restrict__ z_auth) {
    const int j = blockIdx.x * 256 + threadIdx.x;
    const int r0 = blockIdx.y * 4;
    float acc0 = b_auth[j], acc1 = acc0, acc2 = acc0, acc3 = acc0;
    for (int k = 0; k < HP_; ++k) {
        const float kp = k_auth[(size_t)k * N2_ + j];
        acc0 += h[(size_t)(r0 + 0) * HP_ + k] * kp;
        acc1 += h[(size_t)(r0 + 1) * HP_ + k] * kp;
        acc2 += h[(size_t)(r0 + 2) * HP_ + k] * kp;
        acc3 += h[(size_t)(r0 + 3) * HP_ + k] * kp;
    }
#pragma unroll
    for (int r = 0; r < 4; ++r) {
        const int b = r0 + r;
        const int g = b >> 6, a = b & 63;
        const float v = (r == 0) ? acc0 : (r == 1) ? acc1 : (r == 2) ? acc2 : acc3;
        z_auth[((size_t)a * G_ + g) * N2_ + j] = v;
    }
}

__global__ __launch_bounds__(1024) void k_author(const float* __restrict__ z_auth,
                                                 const float* __restrict__ r_auth,
                                                 float* __restrict__ out) {
    const int g = blockIdx.x;
    const int tid = threadIdx.x;
    const int j = tid >> 1;     // gate column 0..511
    const int kh = tid & 1;     // k half

    __shared__ float hs[HA_];
    __shared__ float gs[N2_];

    float rc[64];
#pragma unroll
    for (int kk = 0; kk < 64; ++kk)
        rc[kk] = r_auth[(size_t)(kh * 64 + kk) * N2_ + j];

    float cj = 0.f;
    if (tid < HA_) hs[tid] = 0.f;
    __syncthreads();

    for (int a = 0; a < A_; ++a) {
        float acc = kh ? 0.f : z_auth[((size_t)a * G_ + g) * N2_ + j];
#pragma unroll
        for (int kk = 0; kk < 64; ++kk)
            acc += hs[kh * 64 + kk] * rc[kk];
        acc += __shfl_xor(acc, 1);
        if (!kh) gs[j] = acc;
        __syncthreads();
        if (tid < HA_) {
            const float i_ = sigmoidf_(gs[tid]);
            const float f_ = sigmoidf_(gs[tid + 128]);
            const float gg = gs[tid + 256];
            const float o_ = sigmoidf_(gs[tid + 384]);
            cj = f_ * cj + i_ * tanhf_(gg);
            hs[tid] = o_ * tanhf_(cj);
        }
        __syncthreads();
    }
    if (tid < HA_) out[(size_t)g * HA_ + tid] = hs[tid];
}

// ---------------- launch ----------------
extern "C" void kernel_launch(void* const* d_in, const int* in_sizes, int n_in,
                              void* d_out, int out_size, void* d_ws, size_t ws_size,
                              hipStream_t stream) {
    const float* x       = (const float*)d_in[0];
    const float* w_embed = (const float*)d_in[1];
    const float* b_embed = (const float*)d_in[2];
    const float* k_post  = (const float*)d_in[3];
    const float* r_post  = (const float*)d_in[4];
    const float* b_post  = (const float*)d_in[5];
    const float* k_auth  = (const float*)d_in[6];
    const float* r_auth  = (const float*)d_in[7];
    const float* b_auth  = (const float*)d_in[8];
    float* out = (float*)d_out;

    char* wsb = (char*)d_ws;
    _Float16*       Zq     = (_Float16*)(wsb);                        // 32 MB (one chunk)
    float*          Bmat   = (float*)(wsb + (32ull << 20));           // 3 MB
    _Float16*       Bt16   = (_Float16*)(wsb + (36ull << 20));        // 1.5 MB
    _Float16*       Bfrag  = (_Float16*)(wsb + (38ull << 20));        // 512 KB
    float*          biasZp = (float*)(wsb + (38ull << 20) + (512ull << 10));  // 4 KB
    float*          csave  = (float*)(wsb + (39ull << 20));           // 1 MB
    unsigned short* hsave  = (unsigned short*)(wsb + (40ull << 20));  // 512 KB
    float*          hF32   = (float*)(wsb + (41ull << 20));           // 1 MB
    float*          z_auth = (float*)(wsb + (42ull << 20));           // 2 MB

    // prep
    k_wk    <<<dim3(N1_ / 256, DIN_ / 4), 256, 0, stream>>>(w_embed, k_post, Bmat);
    k_bias_p<<<dim3(N1_ / 256), 256, 0, stream>>>(b_embed, k_post, b_post, biasZp);
    k_t16   <<<dim3(16, 12), 256, 0, stream>>>(Bmat, Bt16);
    k_bfrag <<<dim3(128), 256, 0, stream>>>(r_post, Bfrag);

    // two chunks of 16 timesteps
    for (int ch = 0; ch < 2; ++ch) {
        k_zgemm<<<dim3(512), 512, 0, stream>>>(x, Bt16, biasZp, Zq, ch * TCH);
        k_rec  <<<dim3(64), 1024, 0, stream>>>(Zq, Bfrag, csave, hsave, hF32, ch * TCH);
    }

    // author stage
    k_zauth <<<dim3(N2_ / 256, GA_ / 4), 256, 0, stream>>>(hF32, k_auth, b_auth, z_auth);
    k_author<<<dim3(G_), 1024, 0, stream>>>(z_auth, r_auth, out);
}